// Round 1
// baseline (24.489 us; speedup 1.0000x reference)
//
#include <hip/hip_runtime.h>

#define TBLSZ 4096
#define NSIZES 18
#define DIM 256
#define SEQLEN 8192

// Kernel A: Smix[d] = sum over the 18 tables of the MIXED (row 4096) embedding.
__global__ void NGram_smix_kernel(const float* __restrict__ tables,
                                  float* __restrict__ smix) {
    int d = threadIdx.x; // 256 threads, 1 block
    float s = 0.f;
    for (int t = 0; t < NSIZES; ++t)
        s += tables[((size_t)t * (TBLSZ + 1) + TBLSZ) * DIM + d];
    smix[d] = s;
}

// Kernel B: one wave per position; lane c owns floats [4c..4c+3] of D.
// Fast path (size-3 window dirty -> ALL ids are MIXED): out = Smix/19.
// Slow path (rare, wave-uniform): recompute rolling hash, add corrections.
__global__ __launch_bounds__(256) void NGramEmbedding_73718818668652_kernel(
    const int* __restrict__ byte_ids, const float* __restrict__ tables,
    const float* __restrict__ smix, float* __restrict__ out, int npos)
{
    const int tid0   = blockIdx.x * blockDim.x + threadIdx.x;
    const int stride = gridDim.x * blockDim.x;      // multiple of 64
    const int c = tid0 & 63;                        // float4 chunk of D (invariant)
    const float4 base = ((const float4*)smix)[c];
    const float inv = 1.0f / 19.0f;
    const int total = npos * 64;

    for (int tid = tid0; tid < total; tid += stride) {
        const int pos = tid >> 6;                   // wave-uniform
        const int i   = pos & (SEQLEN - 1);
        const int* row = byte_ids + (pos - i);      // start of this batch row

        float4 acc = base;

        // fast check: is the size-3 backward window all-DNA?
        bool slow = false;
        if (i >= 2) {
            int v0 = row[i], v1 = row[i - 1], v2 = row[i - 2];
            slow = ((unsigned)(v0 - 1) < 4u) & ((unsigned)(v1 - 1) < 4u)
                 & ((unsigned)(v2 - 1) < 4u);
        }

        if (slow) {  // wave-uniform branch
            int h = 0, p = 1;
            for (int j = 0; j < 20; ++j) {
                const int q = i - j;
                const int v = (q >= 0) ? row[q] : 0;
                if ((unsigned)(v - 1) >= 4u) break; // window bad from here on
                h = (h + (v - 1) * p) & (TBLSZ - 1);
                p = (p * 31) & (TBLSZ - 1);
                const int k = j + 1;
                if (k >= 3) {
                    const int t = k - 3;
                    const float4* T4 =
                        (const float4*)(tables + (size_t)t * (TBLSZ + 1) * DIM);
                    float4 g = T4[(size_t)h * (DIM / 4) + c];
                    float4 m = T4[(size_t)TBLSZ * (DIM / 4) + c];
                    acc.x += g.x - m.x; acc.y += g.y - m.y;
                    acc.z += g.z - m.z; acc.w += g.w - m.w;
                }
            }
        }

        float4 r;
        r.x = acc.x * inv; r.y = acc.y * inv;
        r.z = acc.z * inv; r.w = acc.w * inv;
        ((float4*)out)[(size_t)pos * (DIM / 4) + c] = r;
    }
}

extern "C" void kernel_launch(void* const* d_in, const int* in_sizes, int n_in,
                              void* d_out, int out_size, void* d_ws, size_t ws_size,
                              hipStream_t stream) {
    const int*   byte_ids = (const int*)d_in[0];
    const float* tables   = (const float*)d_in[1];
    float* out  = (float*)d_out;
    float* smix = (float*)d_ws;                  // 1 KB scratch
    const int npos = in_sizes[0];                // B*L = 65536

    hipLaunchKernelGGL(NGram_smix_kernel, dim3(1), dim3(256), 0, stream,
                       tables, smix);
    hipLaunchKernelGGL(NGramEmbedding_73718818668652_kernel,
                       dim3(4096), dim3(256), 0, stream,
                       byte_ids, tables, smix, out, npos);
}